// Round 2
// baseline (100.984 us; speedup 1.0000x reference)
//
#include <hip/hip_runtime.h>
#include <hip/hip_bf16.h>

// B=8, T=4096, C=32, D=64. Causal, no 1/sqrt(D) scaling.
constexpr int Bc = 8;
constexpr int Tt = 4096;
constexpr int Dd = 64;

typedef __attribute__((ext_vector_type(8))) short short8;   // 8 bf16 = 4 VGPRs
typedef __attribute__((ext_vector_type(4))) float floatx4;  // MFMA C/D frag
typedef __attribute__((ext_vector_type(4))) __fp16 half4;   // 4 f16 = 2 VGPRs
typedef __attribute__((ext_vector_type(2))) __fp16 half2v;
typedef uint4   __attribute__((may_alias)) uint4_a;
typedef short8  __attribute__((may_alias)) short8_a;
typedef ushort4 __attribute__((may_alias)) ushort4_a;
typedef float4  __attribute__((may_alias)) float4_a;
typedef half4   __attribute__((may_alias)) half4_a;

#define MFMA16(A, B, C)  __builtin_amdgcn_mfma_f32_16x16x32_bf16(A, B, C, 0, 0, 0)
#define MFMAH16(A, B, C) __builtin_amdgcn_mfma_f32_16x16x16f16(A, B, C, 0, 0, 0)
constexpr float LOG2E = 1.4426950408889634f;

// Workspace layout (bytes). Total ~6 MB + 4 KB (ws is 256 MB).
constexpr size_t XB_OFF = 0;                   // xb : [B*T][32] bf16, 64 B rows
constexpr size_t YB_OFF = (size_t)2 << 20;     // Yb : [B*T][32] bf16, 64 B rows
constexpr size_t XT_OFF = (size_t)4 << 20;     // xt : [B*256][32][16] f16, 1 KB/16-key chunk
constexpr size_t WV_OFF = (size_t)6 << 20;     // Wvb: [64][32] bf16 (Wv^T rows)

// ---- fast fp32 -> bf16: round-half-up (u + 0x8000), pack 2 via v_perm ----
__device__ __forceinline__ unsigned rnd16(float x) {
    unsigned u; __builtin_memcpy(&u, &x, 4); return u + 0x8000u;
}
__device__ __forceinline__ unsigned pk_bf2(float lo, float hi) {
    return __builtin_amdgcn_perm(rnd16(hi), rnd16(lo), 0x07060302);
}
__device__ __forceinline__ ushort4 pack4(floatx4 d) {
    union { unsigned u[2]; ushort4 v; } r;
    r.u[0] = pk_bf2(d[0], d[1]);
    r.u[1] = pk_bf2(d[2], d[3]);
    return r.v;
}
__device__ __forceinline__ short8 cvt8(float4 a, float4 b) {
    union { unsigned u[4]; short8 s; } r;
    r.u[0] = pk_bf2(a.x, a.y);
    r.u[1] = pk_bf2(a.z, a.w);
    r.u[2] = pk_bf2(b.x, b.y);
    r.u[3] = pk_bf2(b.z, b.w);
    return r.s;
}

// ---------------------------------------------------------------------------
// R15 == R14 resubmit (round 1 failure was a container/broker flake, audited
// for faults: bounds, barriers, deadlock, LDS races, VGPR budget all clean).
//
// Prepass: one-time format conversion (was redone ~8x per unique tile inside
// the old k-loop staging). Per 64-row slab: xb (bf16 [row][c], S A-frag
// layout), Y = x·(log2e·Wq·Wk^T) (bf16 [q][yc], S B-frag layout), xt (f16
// [16-key chunk][c][key], PV A-frag layout). Block 0 also writes Wv^T bf16.
// Main kernel then loads all MFMA fragments straight from these L2-resident
// buffers: zero LDS / zero barriers in the k-loop.
// ---------------------------------------------------------------------------
__global__ __launch_bounds__(256) void prep_kernel(
    const float* __restrict__ x,
    const float* __restrict__ Wk, const float* __restrict__ Wq,
    const float* __restrict__ Wv,
    char* __restrict__ ws)
{
    __shared__ uint4 sG[128];    // 2 KB: G^T [c'][c] bf16
    __shared__ float sX[2048];   // 8 KB: fp32 slab [64 row][32 c]

    const int bi = blockIdx.x;
    const int b = bi >> 6, ch = bi & 63;
    const int tid = threadIdx.x;
    const int wave = tid >> 6, lane = tid & 63;
    const int ln15 = lane & 15, quad = lane >> 4;
    const size_t bT = (size_t)b * Tt;
    const int r0 = ch * 64;

    // ---- coalesced slab load: wave w covers rows 16w..16w+15, 32 B/thread ----
    const int lr = wave * 16 + ln15;
    const float* xp = x + (bT + r0 + lr) * 32 + quad * 8;
    float4 pX0 = ((const float4_a*)xp)[0];
    float4 pX1 = ((const float4_a*)xp)[1];
    *(float4_a*)(&sX[lr * 32 + quad * 8])     = pX0;
    *(float4_a*)(&sX[lr * 32 + quad * 8 + 4]) = pX1;

    // ---- G = (log2e Wq)·Wk^T [32x32], wave 0 -> sG ----
    if (wave == 0) {
        floatx4 gC[2][2];
        #pragma unroll
        for (int mt = 0; mt < 2; ++mt)
            #pragma unroll
            for (int nt = 0; nt < 2; ++nt) gC[mt][nt] = (floatx4){0.f,0.f,0.f,0.f};
        #pragma unroll
        for (int kt = 0; kt < 2; ++kt) {
            short8 aG[2], bG[2];
            #pragma unroll
            for (int mt = 0; mt < 2; ++mt) {
                const float* qp = Wq + (ln15 + 16*mt)*64 + 32*kt + quad*8;
                float4 a = ((const float4_a*)qp)[0], bb = ((const float4_a*)qp)[1];
                a.x*=LOG2E; a.y*=LOG2E; a.z*=LOG2E; a.w*=LOG2E;
                bb.x*=LOG2E; bb.y*=LOG2E; bb.z*=LOG2E; bb.w*=LOG2E;
                aG[mt] = cvt8(a, bb);
                const float* kp = Wk + (ln15 + 16*mt)*64 + 32*kt + quad*8;
                bG[mt] = cvt8(((const float4_a*)kp)[0], ((const float4_a*)kp)[1]);
            }
            #pragma unroll
            for (int mt = 0; mt < 2; ++mt)
                #pragma unroll
                for (int nt = 0; nt < 2; ++nt)
                    gC[mt][nt] = MFMA16(aG[mt], bG[nt], gC[mt][nt]);
        }
        unsigned short* sGh = (unsigned short*)sG;
        #pragma unroll
        for (int mt = 0; mt < 2; ++mt)
            #pragma unroll
            for (int nt = 0; nt < 2; ++nt)
                *(ushort4_a*)(sGh + (16*nt + ln15)*32 + 16*mt + quad*4)
                    = pack4(gC[mt][nt]);
    }
    __syncthreads();

    // ---- xb: bf16 [row][c] (coalesced 16 B/thread) ----
    union { unsigned u[4]; uint4 v; } xu;
    xu.u[0] = pk_bf2(pX0.x, pX0.y); xu.u[1] = pk_bf2(pX0.z, pX0.w);
    xu.u[2] = pk_bf2(pX1.x, pX1.y); xu.u[3] = pk_bf2(pX1.z, pX1.w);
    *(uint4_a*)(ws + XB_OFF + (size_t)(bT + r0 + lr) * 64 + quad * 16) = xu.v;

    // ---- Y = x·G: 2 MFMA per wave; store bf16 [q][yc] rows ----
    {
        short8 xq = cvt8(pX0, pX1);
        unsigned short* yb = (unsigned short*)(ws + YB_OFF);
        #pragma unroll
        for (int mt = 0; mt < 2; ++mt) {
            union { uint4 u; short8 s; } g;
            g.u = sG[(16*mt + ln15)*4 + quad];
            floatx4 d = (floatx4){0.f,0.f,0.f,0.f};
            d = MFMA16(g.s, xq, d);   // col=q=ln15, row=yc=16mt+quad*4+r
            *(ushort4_a*)(yb + (size_t)(bT + r0 + lr) * 32 + 16*mt + quad*4)
                = pack4(d);
        }
    }

    // ---- xt: f16 [chunk][c][16 key] from LDS transpose ----
    {
        const int kc = tid >> 6;            // 16-key chunk within slab
        const int c = (tid >> 1) & 31, kh = tid & 1;
        float v[8];
        #pragma unroll
        for (int j = 0; j < 8; ++j) v[j] = sX[(kc*16 + kh*8 + j)*32 + c];
        union { unsigned u[4]; uint4 q; } x4;
        #pragma unroll
        for (int j = 0; j < 4; ++j) {
            union { half2v h; unsigned u; } p;
            p.h = __builtin_amdgcn_cvt_pkrtz(v[2*j], v[2*j+1]);
            x4.u[j] = p.u;
        }
        *(uint4_a*)(ws + XT_OFF
                    + ((size_t)((b*256 + ch*4 + kc) * 32 + c)) * 32 + kh * 16)
            = x4.q;
    }

    // ---- Wvb: Wv^T bf16 [d][c'] (block 0, wave 2 only) ----
    if (bi == 0 && wave == 2) {
        const int d = lane;
        unsigned short* wvb = (unsigned short*)(ws + WV_OFF);
        float v[32];
        #pragma unroll
        for (int c2 = 0; c2 < 32; ++c2) v[c2] = Wv[c2*64 + d];
        #pragma unroll
        for (int i2 = 0; i2 < 16; ++i2)
            ((unsigned*)(wvb + d*32))[i2] = pk_bf2(v[2*i2], v[2*i2+1]);
    }
}

// ---------------------------------------------------------------------------
// Main: same algebra/structure as R13 (4 split-K groups x 4 waves, balanced
// (63-pr, pr) phases, additive LDS merge) but the k-loop is barrier-free and
// LDS-free: S A-frags (16 B), Y B-frag (16 B), PV A-frags (8 B) are direct
// coalesced loads from the prepass buffers (L2-resident, b==XCD aligned).
// 2-deep software pipeline on S frags (named aA/aB4, all static indexing);
// PV frags issued at body top (~150 cyc ahead of use).
// Barriers: 3 per phase (merge only) vs ~20 before.
// ---------------------------------------------------------------------------
__global__ __launch_bounds__(1024, 4) void attn_kernel(
    const char* __restrict__ ws, float* __restrict__ out)
{
    __shared__ float sZ[3 * 2048];  // 24 KB: groups 1..3 Z^T dump
    __shared__ float sL[3 * 256];   //  3 KB: groups 1..3 l
    __shared__ uint4 sB[256];       //  4 KB: zb pack round-trip (group 0)

    const int b  = blockIdx.x & 7;
    const int pr = blockIdx.x >> 3;          // 0..31
    const int tid = threadIdx.x;
    const int wave = tid >> 6, lane = tid & 63;
    const int kg = wave >> 2, gw = wave & 3; // split-K group / wave-in-group
    const int ln15 = lane & 15, quad = lane >> 4;
    const size_t bT = (size_t)b * Tt;

    const char* xbB = ws + XB_OFF + bT * 64;
    const char* xtB = ws + XT_OFF + (size_t)b * (256 * 1024);
    const int aOff = ln15 * 64 + quad * 16;  // S A-frag lane offset
    const int xOff = ln15 * 32 + quad * 8;   // PV A-frag lane offset

    for (int phase = 0; phase < 2; ++phase) {
        const int qt = phase ? pr : 63 - pr;
        const int q0 = qt * 64;
        const int qrow = q0 + gw * 16 + ln15;

        // Y B-frag (n=q=ln15, k=yc=quad*8+j), loop-invariant
        short8 bq;
        {
            union { uint4 u; short8 s; } t0;
            t0.u = *(const uint4_a*)(ws + YB_OFF + (size_t)(bT + qrow) * 64
                                     + quad * 16);
            bq = t0.s;
        }

        floatx4 z4[2];  // Z^T acc: (col=q=ln15, row=c'=16mt+quad*4+r)
        z4[0] = (floatx4){0.f,0.f,0.f,0.f};
        z4[1] = (floatx4){0.f,0.f,0.f,0.f};
        float l_lane = 0.f;

        short8 aA[4], aB4[4];  // double-buffered S A-frags

        auto LDA = [&](int k, short8* a) {
            const char* p = xbB + (size_t)k * 4096 + aOff;
            #pragma unroll
            for (int t = 0; t < 4; ++t)
                a[t] = *(const short8_a*)(p + t * 1024);
        };

        auto BODY = [&](int kt, const short8* a) {
            // PV A-frags issued first: consumed after S-MFMA + exp (~150 cyc)
            const char* px = xtB + (size_t)kt * 4096 + xOff;
            half4 xa[8];
            #pragma unroll
            for (int t = 0; t < 4; ++t) {
                xa[2*t]   = *(const half4_a*)(px + t * 1024);
                xa[2*t+1] = *(const half4_a*)(px + t * 1024 + 512);
            }
            // S^T = x_k · Y^T : 4 MFMA (K=32)
            floatx4 s4[4];
            #pragma unroll
            for (int t = 0; t < 4; ++t) {
                floatx4 c0 = (floatx4){0.f,0.f,0.f,0.f};
                s4[t] = MFMA16(a[t], bq, c0);
            }
            // p = exp2(s) in-register (mask only the diagonal tile)
            if (kt == qt) {  // group-uniform branch
                #pragma unroll
                for (int t = 0; t < 4; ++t) {
                    const int keyb = kt*64 + 16*t + quad*4;
                    #pragma unroll
                    for (int r = 0; r < 4; ++r) {
                        float p = (keyb + r <= qrow)
                                  ? __builtin_amdgcn_exp2f(s4[t][r]) : 0.f;
                        s4[t][r] = p; l_lane += p;
                    }
                }
            } else {
                #pragma unroll
                for (int t = 0; t < 4; ++t)
                    #pragma unroll
                    for (int r = 0; r < 4; ++r) {
                        float p = __builtin_amdgcn_exp2f(s4[t][r]);
                        s4[t][r] = p; l_lane += p;
                    }
            }
            // Z^T += x^T · P^T : 8 mfma f16 K=16, P direct from registers
            #pragma unroll
            for (int t = 0; t < 4; ++t) {
                union { half2v h2[2]; half4 h4; } pb;
                pb.h2[0] = __builtin_amdgcn_cvt_pkrtz(s4[t][0], s4[t][1]);
                pb.h2[1] = __builtin_amdgcn_cvt_pkrtz(s4[t][2], s4[t][3]);
                z4[0] = MFMAH16(xa[2*t],   pb.h4, z4[0]);
                z4[1] = MFMAH16(xa[2*t+1], pb.h4, z4[1]);
            }
        };

        // ---- barrier-free pipelined k-loop: kt = kg, kg+4, ... <= qt ----
        int kt = kg;
        if (kt <= qt) {
            LDA(kt, aA);
            while (true) {
                int kn = kt + 4;
                LDA(kn <= qt ? kn : kt, aB4);   // clamped prefetch (in-bounds)
                BODY(kt, aA);
                if (kn > qt) break;
                kt = kn; kn = kt + 4;
                LDA(kn <= qt ? kn : kt, aA);
                BODY(kt, aB4);
                if (kn > qt) break;
                kt = kn;
            }
        }

        // ---- merge 4 groups' (Z^T, l) additively in LDS; group 0 finishes ----
        __syncthreads();
        const int li = gw * 64 + lane;
        if (kg != 0) {
            sL[(kg - 1) * 256 + li] = l_lane;
            float4* zp = (float4*)(sZ + (kg - 1) * 2048);
            zp[li*2 + 0] = make_float4(z4[0][0], z4[0][1], z4[0][2], z4[0][3]);
            zp[li*2 + 1] = make_float4(z4[1][0], z4[1][1], z4[1][2], z4[1][3]);
        }
        __syncthreads();
        if (kg == 0) {
            float l = l_lane + sL[li] + sL[256 + li] + sL[512 + li];
            #pragma unroll
            for (int g = 0; g < 3; ++g) {
                const float4* zp = (const float4*)(sZ + g * 2048);
                float4 za = zp[li*2 + 0], zb2 = zp[li*2 + 1];
                z4[0][0]+=za.x;  z4[0][1]+=za.y;  z4[0][2]+=za.z;  z4[0][3]+=za.w;
                z4[1][0]+=zb2.x; z4[1][1]+=zb2.y; z4[1][2]+=zb2.z; z4[1][3]+=zb2.w;
            }
            l += __shfl_xor(l, 16);   // quads hold disjoint key subsets
            l += __shfl_xor(l, 32);
            const float inv = 1.f / l;
            // Wv^T A-frags from prepass buffer (L2-hot)
            const unsigned short* wvb = (const unsigned short*)(ws + WV_OFF);
            short8 wv_f[4];
            #pragma unroll
            for (int t = 0; t < 4; ++t) {
                union { uint4 u; short8 s; } w0;
                w0.u = *(const uint4_a*)(wvb + (16*t + ln15) * 32 + quad * 8);
                wv_f[t] = w0.s;
            }
            // pack merged Z as bf16 [q][c']; same-wave LDS round-trip
            unsigned short* sZb = (unsigned short*)sB;
            #pragma unroll
            for (int mt = 0; mt < 2; ++mt)
                *(ushort4_a*)(sZb + (gw*16 + ln15)*32 + 16*mt + quad*4)
                    = pack4(z4[mt]);
            union { uint4 u; short8 s; } zb;
            zb.u = sB[(gw*16 + ln15)*4 + quad];
            // O^T = Wv^T · Z^T : 4 MFMA (K=32); col=q=ln15, row=d=16t+quad*4+r
            #pragma unroll
            for (int t = 0; t < 4; ++t) {
                floatx4 o = (floatx4){0.f,0.f,0.f,0.f};
                o = MFMA16(wv_f[t], zb.s, o);
                *(float4_a*)(out + (bT + (size_t)qrow) * Dd + 16*t + quad*4)
                    = make_float4(o[0]*inv, o[1]*inv, o[2]*inv, o[3]*inv);
            }
        }
        __syncthreads();  // sZ/sL/sB free before next phase
    }
}

// ---------------------------------------------------------------------------
extern "C" void kernel_launch(void* const* d_in, const int* in_sizes, int n_in,
                              void* d_out, int out_size, void* d_ws, size_t ws_size,
                              hipStream_t stream)
{
    const float* x  = (const float*)d_in[0];
    const float* Wk = (const float*)d_in[1];   // setup_inputs order: x, Wk, Wq, Wv
    const float* Wq = (const float*)d_in[2];
    const float* Wv = (const float*)d_in[3];
    float* out = (float*)d_out;

    // Prepass: 512 blocks x 256 thr, one 64-row slab each (~2 us).
    prep_kernel<<<512, 256, 0, stream>>>(x, Wk, Wq, Wv, (char*)d_ws);
    // Main: 256 blocks (1/CU, b==XCD), 1024 thr, 31 KB LDS, uniform 65 tiles.
    attn_kernel<<<Bc * 32, 1024, 0, stream>>>((const char*)d_ws, out);
}

// Round 3
// 85.581 us; speedup vs baseline: 1.1800x; 1.1800x over previous
//
#include <hip/hip_runtime.h>
#include <hip/hip_bf16.h>

// B=8, T=4096, C=32, D=64. Causal, no 1/sqrt(D) scaling.
constexpr int Bc = 8;
constexpr int Tt = 4096;
constexpr int Dd = 64;

typedef __attribute__((ext_vector_type(8))) short short8;   // 8 bf16 = 4 VGPRs
typedef __attribute__((ext_vector_type(4))) float floatx4;  // MFMA C/D frag
typedef __attribute__((ext_vector_type(4))) __fp16 half4;   // 4 f16 = 2 VGPRs
typedef __attribute__((ext_vector_type(2))) __fp16 half2v;
typedef uint4   __attribute__((may_alias)) uint4_a;
typedef short8  __attribute__((may_alias)) short8_a;
typedef ushort4 __attribute__((may_alias)) ushort4_a;
typedef float4  __attribute__((may_alias)) float4_a;
typedef half4   __attribute__((may_alias)) half4_a;

#define MFMA16(A, B, C)  __builtin_amdgcn_mfma_f32_16x16x32_bf16(A, B, C, 0, 0, 0)
#define MFMAH16(A, B, C) __builtin_amdgcn_mfma_f32_16x16x16f16(A, B, C, 0, 0, 0)
constexpr float LOG2E = 1.4426950408889634f;

// Workspace layout (bytes). Total ~6 MB + 4 KB (ws is 256 MB).
constexpr size_t XB_OFF = 0;                   // xb : [B*T][32] bf16, 64 B rows
constexpr size_t YB_OFF = (size_t)2 << 20;     // Yb : [B*T][32] bf16, 64 B rows
constexpr size_t XT_OFF = (size_t)4 << 20;     // xt : [B*256][32][16] f16, 1 KB/16-key chunk
constexpr size_t WV_OFF = (size_t)6 << 20;     // Wvb: [64][32] bf16 (Wv^T rows)

// ---- fast fp32 -> bf16: round-half-up (u + 0x8000), pack 2 via v_perm ----
__device__ __forceinline__ unsigned rnd16(float x) {
    unsigned u; __builtin_memcpy(&u, &x, 4); return u + 0x8000u;
}
__device__ __forceinline__ unsigned pk_bf2(float lo, float hi) {
    return __builtin_amdgcn_perm(rnd16(hi), rnd16(lo), 0x07060302);
}
__device__ __forceinline__ ushort4 pack4(floatx4 d) {
    union { unsigned u[2]; ushort4 v; } r;
    r.u[0] = pk_bf2(d[0], d[1]);
    r.u[1] = pk_bf2(d[2], d[3]);
    return r.v;
}
__device__ __forceinline__ short8 cvt8(float4 a, float4 b) {
    union { unsigned u[4]; short8 s; } r;
    r.u[0] = pk_bf2(a.x, a.y);
    r.u[1] = pk_bf2(a.z, a.w);
    r.u[2] = pk_bf2(b.x, b.y);
    r.u[3] = pk_bf2(b.z, b.w);
    return r.s;
}

// ---------------------------------------------------------------------------
// Prepass (unchanged from R14/R15, verified): per 64-row slab write xb (bf16
// [row][c], S A-frag layout), Y = x·(log2e·Wq·Wk^T) (bf16 [q][yc], S B-frag
// layout), xt (f16 [16-key chunk][c][key], PV A-frag layout). Block 0 also
// writes Wv^T bf16.
// ---------------------------------------------------------------------------
__global__ __launch_bounds__(256) void prep_kernel(
    const float* __restrict__ x,
    const float* __restrict__ Wk, const float* __restrict__ Wq,
    const float* __restrict__ Wv,
    char* __restrict__ ws)
{
    __shared__ uint4 sG[128];    // 2 KB: G^T [c'][c] bf16
    __shared__ float sX[2048];   // 8 KB: fp32 slab [64 row][32 c]

    const int bi = blockIdx.x;
    const int b = bi >> 6, ch = bi & 63;
    const int tid = threadIdx.x;
    const int wave = tid >> 6, lane = tid & 63;
    const int ln15 = lane & 15, quad = lane >> 4;
    const size_t bT = (size_t)b * Tt;
    const int r0 = ch * 64;

    const int lr = wave * 16 + ln15;
    const float* xp = x + (bT + r0 + lr) * 32 + quad * 8;
    float4 pX0 = ((const float4_a*)xp)[0];
    float4 pX1 = ((const float4_a*)xp)[1];
    *(float4_a*)(&sX[lr * 32 + quad * 8])     = pX0;
    *(float4_a*)(&sX[lr * 32 + quad * 8 + 4]) = pX1;

    if (wave == 0) {
        floatx4 gC[2][2];
        #pragma unroll
        for (int mt = 0; mt < 2; ++mt)
            #pragma unroll
            for (int nt = 0; nt < 2; ++nt) gC[mt][nt] = (floatx4){0.f,0.f,0.f,0.f};
        #pragma unroll
        for (int kt = 0; kt < 2; ++kt) {
            short8 aG[2], bG[2];
            #pragma unroll
            for (int mt = 0; mt < 2; ++mt) {
                const float* qp = Wq + (ln15 + 16*mt)*64 + 32*kt + quad*8;
                float4 a = ((const float4_a*)qp)[0], bb = ((const float4_a*)qp)[1];
                a.x*=LOG2E; a.y*=LOG2E; a.z*=LOG2E; a.w*=LOG2E;
                bb.x*=LOG2E; bb.y*=LOG2E; bb.z*=LOG2E; bb.w*=LOG2E;
                aG[mt] = cvt8(a, bb);
                const float* kp = Wk + (ln15 + 16*mt)*64 + 32*kt + quad*8;
                bG[mt] = cvt8(((const float4_a*)kp)[0], ((const float4_a*)kp)[1]);
            }
            #pragma unroll
            for (int mt = 0; mt < 2; ++mt)
                #pragma unroll
                for (int nt = 0; nt < 2; ++nt)
                    gC[mt][nt] = MFMA16(aG[mt], bG[nt], gC[mt][nt]);
        }
        unsigned short* sGh = (unsigned short*)sG;
        #pragma unroll
        for (int mt = 0; mt < 2; ++mt)
            #pragma unroll
            for (int nt = 0; nt < 2; ++nt)
                *(ushort4_a*)(sGh + (16*nt + ln15)*32 + 16*mt + quad*4)
                    = pack4(gC[mt][nt]);
    }
    __syncthreads();

    // xb: bf16 [row][c]
    union { unsigned u[4]; uint4 v; } xu;
    xu.u[0] = pk_bf2(pX0.x, pX0.y); xu.u[1] = pk_bf2(pX0.z, pX0.w);
    xu.u[2] = pk_bf2(pX1.x, pX1.y); xu.u[3] = pk_bf2(pX1.z, pX1.w);
    *(uint4_a*)(ws + XB_OFF + (size_t)(bT + r0 + lr) * 64 + quad * 16) = xu.v;

    // Y = x·G: 2 MFMA per wave; bf16 [q][yc] rows
    {
        short8 xq = cvt8(pX0, pX1);
        unsigned short* yb = (unsigned short*)(ws + YB_OFF);
        #pragma unroll
        for (int mt = 0; mt < 2; ++mt) {
            union { uint4 u; short8 s; } g;
            g.u = sG[(16*mt + ln15)*4 + quad];
            floatx4 d = (floatx4){0.f,0.f,0.f,0.f};
            d = MFMA16(g.s, xq, d);   // col=q=ln15, row=yc=16mt+quad*4+r
            *(ushort4_a*)(yb + (size_t)(bT + r0 + lr) * 32 + 16*mt + quad*4)
                = pack4(d);
        }
    }

    // xt: f16 [chunk][c][16 key] from LDS transpose
    {
        const int kc = tid >> 6;
        const int c = (tid >> 1) & 31, kh = tid & 1;
        float v[8];
        #pragma unroll
        for (int j = 0; j < 8; ++j) v[j] = sX[(kc*16 + kh*8 + j)*32 + c];
        union { unsigned u[4]; uint4 q; } x4;
        #pragma unroll
        for (int j = 0; j < 4; ++j) {
            union { half2v h; unsigned u; } p;
            p.h = __builtin_amdgcn_cvt_pkrtz(v[2*j], v[2*j+1]);
            x4.u[j] = p.u;
        }
        *(uint4_a*)(ws + XT_OFF
                    + ((size_t)((b*256 + ch*4 + kc) * 32 + c)) * 32 + kh * 16)
            = x4.q;
    }

    // Wvb: Wv^T bf16 [d][c'] (block 0, wave 2 only)
    if (bi == 0 && wave == 2) {
        const int d = lane;
        unsigned short* wvb = (unsigned short*)(ws + WV_OFF);
        float v[32];
        #pragma unroll
        for (int c2 = 0; c2 < 32; ++c2) v[c2] = Wv[c2*64 + d];
        #pragma unroll
        for (int i2 = 0; i2 < 16; ++i2)
            ((unsigned*)(wvb + d*32))[i2] = pk_bf2(v[2*i2], v[2*i2+1]);
    }
}

// ---------------------------------------------------------------------------
// R16 main: ONE WAVE PER (q-tile x k-tile) PROCESSING.
// R14's diagnosis: each tile's 8 KB of fragments (x_k A-frags + xt PV-frags)
// was loaded redundantly by all 4 waves of a split-K group -> 530 MB through
// the L1s (~14 us of TCP occupancy) + collapsed pipeline (VGPR=56) = 40.8 us.
// Now each wave owns the FULL 64 q columns of a tile (4 B-frags bq[nt], 4
// accumulator pairs z4[nt]) so every (q-tile, kt) pair is loaded exactly once:
// 4x less L1 traffic, and each body is 48 MFMA + 64 exp2 (~600 cyc) against
// 12 load instrs -> latency hides under compute at 2 waves/SIMD.
// Block = 512 thr = 8 waves = 2 q-tiles (heavy 63-u paired with light u) x
// 4 split-K groups; wave w -> SIMD w&3 puts one heavy + one light wave per
// SIMD: per-SIMD work is exactly 63 tiles, uniform chip-wide. Grid 256
// (1/CU, b == XCD == blockIdx&7 matches prepass data placement).
// One __syncthreads total; merge via conflict-free [comp][lane] float4 LDS;
// per-wave parallel epilogue (wave kg outputs nt=kg).
// sched_barrier(0) after each body's load block stops the compiler from
// sinking loads to point-of-use (the VGPR=56 syndrome).
// ---------------------------------------------------------------------------
__global__ __launch_bounds__(512, 2) void attn_kernel(
    const char* __restrict__ ws, float* __restrict__ out)
{
    __shared__ float4 sZm[2][4][4][2][64];  // 64 KB [h][nt][kg][comp][lane]
    __shared__ float  sLm[2][4][4][64];     //  8 KB [h][nt][kg][lane]
    __shared__ uint4  sB4[8][64];           //  8 KB per-wave Z pack region

    const int b = blockIdx.x & 7;
    const int u = blockIdx.x >> 3;           // 0..31
    const int tid = threadIdx.x;
    const int wave = tid >> 6, lane = tid & 63;
    const int h = wave >> 2, kg = wave & 3;  // q-tile half / split-K group
    const int ln15 = lane & 15, quad = lane >> 4;
    const size_t bT = (size_t)b * Tt;

    const int qt = h ? u : (63 - u);         // paired heavy/light per SIMD
    const int q0 = qt * 64;

    const char* xbB = ws + XB_OFF + bT * 64;
    const char* xtB = ws + XT_OFF + (size_t)b * (256 * 1024);
    const int aOff = ln15 * 64 + quad * 16;  // S A-frag lane offset
    const int xOff = ln15 * 32 + quad * 8;   // PV A-frag lane offset

    // Y B-frags for all 4 q-subtiles (n=q=ln15, k=yc=quad*8+j), loop-invariant
    short8 bq[4];
    #pragma unroll
    for (int nt = 0; nt < 4; ++nt) {
        union { uint4 u4; short8 s; } t0;
        t0.u4 = *(const uint4_a*)(ws + YB_OFF
                 + (size_t)(bT + q0 + 16*nt + ln15) * 64 + quad * 16);
        bq[nt] = t0.s;
    }

    floatx4 z4[4][2];   // Z^T acc per nt: (col=q=ln15, row=c'=16mt+quad*4+r)
    float lq[4];
    #pragma unroll
    for (int nt = 0; nt < 4; ++nt) {
        z4[nt][0] = (floatx4){0.f,0.f,0.f,0.f};
        z4[nt][1] = (floatx4){0.f,0.f,0.f,0.f};
        lq[nt] = 0.f;
    }

    short8 aA[4], aB4[4];   // double-buffered S A-frags (shared across nt)

    auto LDA = [&](int k, short8* a) {
        const char* p = xbB + (size_t)k * 4096 + aOff;
        #pragma unroll
        for (int t = 0; t < 4; ++t)
            a[t] = *(const short8_a*)(p + t * 1024);
    };

    auto BODY = [&](int kt, const short8* a) {
        // PV A-frags issued first (consumed after 16 S-MFMA + 64 exp)
        const char* px = xtB + (size_t)kt * 4096 + xOff;
        half4 xa[8];
        #pragma unroll
        for (int t = 0; t < 4; ++t) {
            xa[2*t]   = *(const half4_a*)(px + t * 1024);
            xa[2*t+1] = *(const half4_a*)(px + t * 1024 + 512);
        }
        __builtin_amdgcn_sched_barrier(0);   // pin loads above the MFMA storm
        #pragma unroll
        for (int nt = 0; nt < 4; ++nt) {
            // S^T = x_k · Y^T : 4 MFMA (K=32) for this q-subtile
            floatx4 s4[4];
            #pragma unroll
            for (int t = 0; t < 4; ++t) {
                floatx4 c0 = (floatx4){0.f,0.f,0.f,0.f};
                s4[t] = MFMA16(a[t], bq[nt], c0);
            }
            // p = exp2(s) in-register (mask only the diagonal tile)
            if (kt == qt) {  // wave-uniform branch
                const int qrow = q0 + 16*nt + ln15;
                #pragma unroll
                for (int t = 0; t < 4; ++t) {
                    const int keyb = kt*64 + 16*t + quad*4;
                    #pragma unroll
                    for (int r = 0; r < 4; ++r) {
                        float p = (keyb + r <= qrow)
                                  ? __builtin_amdgcn_exp2f(s4[t][r]) : 0.f;
                        s4[t][r] = p; lq[nt] += p;
                    }
                }
            } else {
                #pragma unroll
                for (int t = 0; t < 4; ++t)
                    #pragma unroll
                    for (int r = 0; r < 4; ++r) {
                        float p = __builtin_amdgcn_exp2f(s4[t][r]);
                        s4[t][r] = p; lq[nt] += p;
                    }
            }
            // Z^T += x^T · P^T : 8 mfma f16 K=16, P direct from registers
            #pragma unroll
            for (int t = 0; t < 4; ++t) {
                union { half2v h2[2]; half4 h4; } pb;
                pb.h2[0] = __builtin_amdgcn_cvt_pkrtz(s4[t][0], s4[t][1]);
                pb.h2[1] = __builtin_amdgcn_cvt_pkrtz(s4[t][2], s4[t][3]);
                z4[nt][0] = MFMAH16(xa[2*t],   pb.h4, z4[nt][0]);
                z4[nt][1] = MFMAH16(xa[2*t+1], pb.h4, z4[nt][1]);
            }
        }
    };

    // ---- barrier-free pipelined k-loop: kt = kg, kg+4, ... <= qt ----
    int kt = kg;
    if (kt <= qt) {
        LDA(kt, aA);
        while (true) {
            int kn = kt + 4;
            LDA(kn <= qt ? kn : kt, aB4);   // clamped prefetch (in-bounds)
            BODY(kt, aA);
            if (kn > qt) break;
            kt = kn; kn = kt + 4;
            LDA(kn <= qt ? kn : kt, aA);
            BODY(kt, aB4);
            if (kn > qt) break;
            kt = kn;
        }
    }

    // ---- merge 4 split-K partials in LDS (single barrier) ----
    #pragma unroll
    for (int nt = 0; nt < 4; ++nt) {
        sZm[h][nt][kg][0][lane] = make_float4(z4[nt][0][0], z4[nt][0][1],
                                              z4[nt][0][2], z4[nt][0][3]);
        sZm[h][nt][kg][1][lane] = make_float4(z4[nt][1][0], z4[nt][1][1],
                                              z4[nt][1][2], z4[nt][1][3]);
        sLm[h][nt][kg][lane] = lq[nt];
    }
    __syncthreads();

    // ---- per-wave epilogue: wave (h,kg) finishes q-subtile nt = kg ----
    {
        const int nt = kg;
        float4 zm0 = make_float4(0.f,0.f,0.f,0.f);
        float4 zm1 = make_float4(0.f,0.f,0.f,0.f);
        float l = 0.f;
        #pragma unroll
        for (int g = 0; g < 4; ++g) {
            float4 a0 = sZm[h][nt][g][0][lane];
            float4 a1 = sZm[h][nt][g][1][lane];
            zm0.x+=a0.x; zm0.y+=a0.y; zm0.z+=a0.z; zm0.w+=a0.w;
            zm1.x+=a1.x; zm1.y+=a1.y; zm1.z+=a1.z; zm1.w+=a1.w;
            l += sLm[h][nt][g][lane];
        }
        l += __shfl_xor(l, 16);    // quads hold disjoint key subsets
        l += __shfl_xor(l, 32);
        const float inv = 1.f / l;

        // Wv^T A-frags (L2-hot prepass buffer)
        const unsigned short* wvb = (const unsigned short*)(ws + WV_OFF);
        short8 wv_f[4];
        #pragma unroll
        for (int t = 0; t < 4; ++t) {
            union { uint4 u4; short8 s; } w0;
            w0.u4 = *(const uint4_a*)(wvb + (16*t + ln15) * 32 + quad * 8);
            wv_f[t] = w0.s;
        }
        // pack merged Z as bf16 [q(16)][c'(32)]; same-wave LDS round-trip
        unsigned short* sZb = (unsigned short*)&sB4[wave][0];
        floatx4 zv0 = (floatx4){zm0.x, zm0.y, zm0.z, zm0.w};
        floatx4 zv1 = (floatx4){zm1.x, zm1.y, zm1.z, zm1.w};
        *(ushort4_a*)(sZb + ln15*32 + quad*4)      = pack4(zv0);
        *(ushort4_a*)(sZb + ln15*32 + 16 + quad*4) = pack4(zv1);
        union { uint4 u4; short8 s; } zb;
        zb.u4 = sB4[wave][ln15*4 + quad];
        // O^T = Wv^T · Z^T : 4 MFMA (K=32); col=q=ln15, row=d=16t+quad*4+r
        const int qrow = q0 + 16*nt + ln15;
        #pragma unroll
        for (int t = 0; t < 4; ++t) {
            floatx4 o = (floatx4){0.f,0.f,0.f,0.f};
            o = MFMA16(wv_f[t], zb.s, o);
            *(float4_a*)(out + (bT + (size_t)qrow) * Dd + 16*t + quad*4)
                = make_float4(o[0]*inv, o[1]*inv, o[2]*inv, o[3]*inv);
        }
    }
}

// ---------------------------------------------------------------------------
extern "C" void kernel_launch(void* const* d_in, const int* in_sizes, int n_in,
                              void* d_out, int out_size, void* d_ws, size_t ws_size,
                              hipStream_t stream)
{
    const float* x  = (const float*)d_in[0];
    const float* Wk = (const float*)d_in[1];   // setup_inputs order: x, Wk, Wq, Wv
    const float* Wq = (const float*)d_in[2];
    const float* Wv = (const float*)d_in[3];
    float* out = (float*)d_out;

    // Prepass: 512 blocks x 256 thr, one 64-row slab each.
    prep_kernel<<<512, 256, 0, stream>>>(x, Wk, Wq, Wv, (char*)d_ws);
    // Main: 256 blocks (1/CU, b==XCD), 512 thr, 80 KB LDS.
    attn_kernel<<<Bc * 32, 512, 0, stream>>>((const char*)d_ws, out);
}